// Round 3
// baseline (403.708 us; speedup 1.0000x reference)
//
#include <hip/hip_runtime.h>

// Problem constants (from reference)
#define B_     8
#define A_     60000
#define C_     150        // 1 + 10+19+39+69+12
#define G_     20
#define T_     5
#define ROWS   21         // G+1 (row 0 = pad/zero row)
#define NANCH  (B_ * A_)          // 480000
#define NTOT   (B_ * A_ * C_)     // 72,000,000
#define NCHUNK (NTOT / 4)         // 18,000,000 float4 chunks
#define NTILE  (NCHUNK / 64)      // 281,250 wave-tiles (64 chunks = 1 KB each)
#define TABN   (B_ * ROWS * C_)   // 25200
#define BETA_  (1.0f / 9.0f)
#define NBLK   8192
#define TPB    256
#define FTPB   1024

typedef float f4 __attribute__((ext_vector_type(4)));

// ---------------------------------------------------------------------------
// Kernel 1: build the 0/1 label table tab[b][g][c].
//   c==0       : label for the binary head = (g>0)
//   c in head i: 1 iff any of the T gt labels for (b, g-1, head i) equals class
//   g==0       : all zeros (pad row; covers labels_bin in {-1,0})
// ---------------------------------------------------------------------------
__global__ void build_table(const int* __restrict__ gt_labels,
                            float* __restrict__ tab) {
    int i = blockIdx.x * blockDim.x + threadIdx.x;
    if (i >= TABN) return;
    int c  = i % C_;
    int bg = i / C_;
    int g  = bg % ROWS;
    int b  = bg / ROWS;
    float v = 0.0f;
    if (g > 0) {
        if (c == 0) {
            v = 1.0f;
        } else {
            int cc = c - 1;   // head offsets: 0,10,29,68,137 ; sizes 10,19,39,69,12
            int head, k;
            if      (cc < 10)  { head = 0; k = cc; }
            else if (cc < 29)  { head = 1; k = cc - 10; }
            else if (cc < 68)  { head = 2; k = cc - 29; }
            else if (cc < 137) { head = 3; k = cc - 68; }
            else               { head = 4; k = cc - 137; }
            const int* lp = gt_labels + ((b * G_ + (g - 1)) * 5 + head) * T_;
            v = (lp[0] == k || lp[1] == k || lp[2] == k ||
                 lp[3] == k || lp[4] == k) ? 1.0f : 0.0f;
        }
    }
    tab[i] = v;
}

// Block-wide sum over NW waves; result valid only in threadIdx.x == 0.
template <int NW>
__device__ __forceinline__ float block_reduce_sum(float v, float* sm) {
    #pragma unroll
    for (int off = 32; off > 0; off >>= 1) v += __shfl_down(v, off, 64);
    int lane = threadIdx.x & 63, w = threadIdx.x >> 6;
    if (lane == 0) sm[w] = v;
    __syncthreads();
    float r = 0.0f;
    if (threadIdx.x == 0) {
        #pragma unroll
        for (int i = 0; i < NW; ++i) r += sm[i];
    }
    __syncthreads();
    return r;
}

__device__ __forceinline__ float sl1(float n) {
    return (n < BETA_) ? (0.5f / BETA_) * n * n : n - 0.5f * BETA_;
}

// Focal term for one element, label L in {0,1}, mask mf in {0,1}.
// s = (2L-1)x ; term = mf * (0.75 - 0.5L) * (1-sigmoid(s))^2 * log(1+exp(-s))
__device__ __forceinline__ float focal_term(float x, float L, float mf) {
    float s     = (L + L - 1.0f) * x;
    float t     = __expf(-s);
    float denom = 1.0f + t;
    float om    = t * __builtin_amdgcn_rcpf(denom);   // 1 - sigmoid(s)
    float ld    = __logf(denom);                      // log(1 + exp(-s))
    return mf * fmaf(L, -0.5f, 0.75f) * (om * om) * ld;
}

// ---------------------------------------------------------------------------
// Process one 1 KB wave-tile (64 consecutive chunks, 256 consecutive elements
// spanning <= 3 anchors). `t` is wave-uniform (derived from a readfirstlane'd
// wave id), so e0/a0/c0/b0 and the <=3 label fetches all live on the SCALAR
// pipe (s_load, SALU) and the fast/slow decision is a uniform s_cbranch.
// Fast path (~73% of tiles): pure math, zero addressing VALU.
// ---------------------------------------------------------------------------
__device__ __forceinline__ float tile_term(f4 x, int t, int lane,
                                           const int* __restrict__ lb,
                                           const float* __restrict__ tab) {
    const int e0 = t << 8;             // first element of tile (t*256)
    const int a0 = e0 / C_;            // scalar magic-mul div
    const int la0 = lb[a0];
    const int la1 = lb[min(a0 + 1, NANCH - 1)];
    const int la2 = lb[min(a0 + 2, NANCH - 1)];
    float acc = 0.0f;
    float xs[4] = {x.x, x.y, x.z, x.w};
    if ((la0 | la1 | la2) == 0) {
        // ---- fast path: every element in tile has label 0, mask 1 ----
        #pragma unroll
        for (int j = 0; j < 4; ++j) {
            float u     = __expf(xs[j]);                       // exp(x)
            float denom = 1.0f + u;
            float om    = u * __builtin_amdgcn_rcpf(denom);    // sigmoid(x)
            acc += 0.75f * (om * om) * __logf(denom);
        }
    } else {
        // ---- general path: per-lane anchor recovery (2 compares, no div) ----
        const int c0 = e0 - a0 * C_;
        const int b0 = a0 / A_;
        const int nb = (b0 + 1) * A_;         // first anchor of next batch
        int off = c0 + (lane << 2);           // 0 .. 149+252 < 450
        int da  = (off >= C_) + (off >= 2 * C_);
        int a   = a0 + da;
        int cc  = off - da * C_;              // 0..149
        int la  = (da == 0) ? la0 : ((da == 1) ? la1 : la2);
        int lnx = (da == 0) ? la1 : la2;      // label of a+1 (da==2 never crosses)
        int bA  = b0 + (a >= nb);
        int bB  = b0 + (a + 1 >= nb);
        int rowA = (bA * ROWS + max(la, 0)) * C_;
        int rowB = (bB * ROWS + max(lnx, 0)) * C_;
        float mA = (la  > -1) ? 1.0f : 0.0f;
        float mB = (lnx > -1) ? 1.0f : 0.0f;
        #pragma unroll
        for (int j = 0; j < 4; ++j) {
            int cj = cc + j;
            if (cj < C_) acc += focal_term(xs[j], tab[rowA + cj], mA);
            else         acc += focal_term(xs[j], tab[rowB + cj - C_], mB);
        }
    }
    return acc;
}

// ---------------------------------------------------------------------------
// Kernel 2 (fused): smooth-L1 regression + positive count + focal cls sum.
// Writes per-block partials {reg, cls, cnt} -> no atomics, no pre-zeroing.
// ---------------------------------------------------------------------------
__global__ __launch_bounds__(TPB) void fused_kernel(
        const float* __restrict__ conf,
        const float* __restrict__ pred, const float* __restrict__ gtl,
        const int*   __restrict__ lb,   const float* __restrict__ tab,
        float* __restrict__ partials) {
    __shared__ float sm[4];
    float reg = 0.0f, cls = 0.0f, cnt = 0.0f;
    const int tid    = blockIdx.x * TPB + threadIdx.x;
    const int stride = gridDim.x * TPB;

    // ---- regression over anchors (5% positives gather pred/gt float4) ----
    for (int a = tid; a < NANCH; a += stride) {
        int l = lb[a];
        if (l > 0) {
            cnt += 1.0f;
            float4 p = ((const float4*)pred)[a];
            float4 g = ((const float4*)gtl)[a];
            reg += sl1(fabsf(p.x - g.x)) + sl1(fabsf(p.y - g.y)) +
                   sl1(fabsf(p.z - g.z)) + sl1(fabsf(p.w - g.w));
        }
    }

    // ---- focal cls over 281,250 wave-tiles, unroll-4, loads hoisted ----
    const f4* cp = (const f4*)conf;
    const int lane = threadIdx.x & 63;
    const int wv   = __builtin_amdgcn_readfirstlane(threadIdx.x >> 6);
    const int nw   = gridDim.x * (TPB / 64);           // total waves
    int t = blockIdx.x * (TPB / 64) + wv;
    for (; t + 3 * nw < NTILE; t += 4 * nw) {
        const int t0 = t, t1 = t + nw, t2 = t + 2 * nw, t3 = t + 3 * nw;
        f4 x0 = __builtin_nontemporal_load(cp + (t0 << 6) + lane);
        f4 x1 = __builtin_nontemporal_load(cp + (t1 << 6) + lane);
        f4 x2 = __builtin_nontemporal_load(cp + (t2 << 6) + lane);
        f4 x3 = __builtin_nontemporal_load(cp + (t3 << 6) + lane);
        cls += tile_term(x0, t0, lane, lb, tab);
        cls += tile_term(x1, t1, lane, lb, tab);
        cls += tile_term(x2, t2, lane, lb, tab);
        cls += tile_term(x3, t3, lane, lb, tab);
    }
    for (; t < NTILE; t += nw) {
        f4 x = __builtin_nontemporal_load(cp + (t << 6) + lane);
        cls += tile_term(x, t, lane, lb, tab);
    }

    float rb = block_reduce_sum<TPB / 64>(reg, sm);
    float cb = block_reduce_sum<TPB / 64>(cls, sm);
    float nb = block_reduce_sum<TPB / 64>(cnt, sm);
    if (threadIdx.x == 0) {
        float4 w; w.x = rb; w.y = cb; w.z = nb; w.w = 0.0f;
        ((float4*)partials)[blockIdx.x] = w;
    }
}

// ---------------------------------------------------------------------------
// Kernel 3: reduce per-block partials, write the two scalar outputs.
// ---------------------------------------------------------------------------
__global__ __launch_bounds__(FTPB) void finalize(
        const float* __restrict__ partials, float* __restrict__ out) {
    __shared__ float sm[FTPB / 64];
    float r = 0.0f, c = 0.0f, n = 0.0f;
    for (int i = threadIdx.x; i < NBLK; i += FTPB) {
        float4 p = ((const float4*)partials)[i];
        r += p.x; c += p.y; n += p.z;
    }
    r = block_reduce_sum<FTPB / 64>(r, sm);
    c = block_reduce_sum<FTPB / 64>(c, sm);
    n = block_reduce_sum<FTPB / 64>(n, sm);
    if (threadIdx.x == 0) {
        float np = fmaxf(1.0f, n);
        out[0] = r / (np * 4.0f);
        out[1] = c / (np * 6.0f);
    }
}

extern "C" void kernel_launch(void* const* d_in, const int* in_sizes, int n_in,
                              void* d_out, int out_size, void* d_ws, size_t ws_size,
                              hipStream_t stream) {
    const float* conf = (const float*)d_in[0];
    const float* pred = (const float*)d_in[1];
    const float* gt   = (const float*)d_in[2];
    const int*   gtl  = (const int*)d_in[3];
    // d_in[4] = counts: unused by the reference computation
    const int*   lb   = (const int*)d_in[5];
    float* out      = (float*)d_out;
    float* partials = (float*)d_ws;                 // NBLK float4 = 128 KB
    float* tab      = (float*)d_ws + 4 * NBLK;      // 25200 floats (100 KB)

    build_table<<<(TABN + TPB - 1) / TPB, TPB, 0, stream>>>(gtl, tab);
    fused_kernel<<<NBLK, TPB, 0, stream>>>(conf, pred, gt, lb, tab, partials);
    finalize<<<1, FTPB, 0, stream>>>(partials, out);
}

// Round 4
// 398.128 us; speedup vs baseline: 1.0140x; 1.0140x over previous
//
#include <hip/hip_runtime.h>

// Problem constants (from reference)
#define B_     8
#define A_     60000
#define C_     150        // 1 + 10+19+39+69+12
#define G_     20
#define T_     5
#define ROWS   21         // G+1 (row 0 = pad/zero row)
#define NANCH  (B_ * A_)          // 480000
#define NTOT   (B_ * A_ * C_)     // 72,000,000
#define NCHUNK (NTOT / 4)         // 18,000,000
#define TABN   (B_ * ROWS * C_)   // 25200
#define BETA_  (1.0f / 9.0f)
#define NBLK   8192
#define TPB    256
#define FTPB   1024

typedef float f4 __attribute__((ext_vector_type(4)));

// ---------------------------------------------------------------------------
// Kernel 1: build the 0/1 label table tab[b][g][c].
//   c==0       : label for the binary head = (g>0)
//   c in head i: 1 iff any of the T gt labels for (b, g-1, head i) equals class
//   g==0       : all zeros (pad row; covers labels_bin in {-1,0})
// ---------------------------------------------------------------------------
__global__ void build_table(const int* __restrict__ gt_labels,
                            float* __restrict__ tab) {
    int i = blockIdx.x * blockDim.x + threadIdx.x;
    if (i >= TABN) return;
    int c  = i % C_;
    int bg = i / C_;
    int g  = bg % ROWS;
    int b  = bg / ROWS;
    float v = 0.0f;
    if (g > 0) {
        if (c == 0) {
            v = 1.0f;
        } else {
            int cc = c - 1;   // head offsets: 0,10,29,68,137 ; sizes 10,19,39,69,12
            int head, k;
            if      (cc < 10)  { head = 0; k = cc; }
            else if (cc < 29)  { head = 1; k = cc - 10; }
            else if (cc < 68)  { head = 2; k = cc - 29; }
            else if (cc < 137) { head = 3; k = cc - 68; }
            else               { head = 4; k = cc - 137; }
            const int* lp = gt_labels + ((b * G_ + (g - 1)) * 5 + head) * T_;
            v = (lp[0] == k || lp[1] == k || lp[2] == k ||
                 lp[3] == k || lp[4] == k) ? 1.0f : 0.0f;
        }
    }
    tab[i] = v;
}

// Block-wide sum over NW waves; result valid only in threadIdx.x == 0.
template <int NW>
__device__ __forceinline__ float block_reduce_sum(float v, float* sm) {
    #pragma unroll
    for (int off = 32; off > 0; off >>= 1) v += __shfl_down(v, off, 64);
    int lane = threadIdx.x & 63, w = threadIdx.x >> 6;
    if (lane == 0) sm[w] = v;
    __syncthreads();
    float r = 0.0f;
    if (threadIdx.x == 0) {
        #pragma unroll
        for (int i = 0; i < NW; ++i) r += sm[i];
    }
    __syncthreads();
    return r;
}

__device__ __forceinline__ float sl1(float n) {
    return (n < BETA_) ? (0.5f / BETA_) * n * n : n - 0.5f * BETA_;
}

// Focal term for one element, label L in {0,1}, mask mf in {0,1}.
// s = (2L-1)x ; term = mf * (0.75 - 0.5L) * (1-sigmoid(s))^2 * log(1+exp(-s))
__device__ __forceinline__ float focal_term(float x, float L, float mf) {
    float s     = (L + L - 1.0f) * x;
    float t     = __expf(-s);
    float denom = 1.0f + t;
    float om    = t * __builtin_amdgcn_rcpf(denom);   // 1 - sigmoid(s)
    float ld    = __logf(denom);                      // log(1 + exp(-s))
    return mf * fmaf(L, -0.5f, 0.75f) * (om * om) * ld;
}

// Process one float4 chunk of confidence. Wave-uniform two-path:
//  - if ALL 64 lanes see labels {0,0}: closed-form L=0, mask=1 (no gathers)
//  - else: general table path for the WHOLE wave (correct for l<=0 too,
//    since row 0 of tab is all zeros and mask kills l==-1)
__device__ __forceinline__ float process_chunk(f4 x, int a, int c,
                                               int l0, int l1,
                                               const float* __restrict__ tab) {
    float acc = 0.0f;
    float xs[4] = {x.x, x.y, x.z, x.w};
    if (!__any((l0 | l1) != 0)) {
        // ---- fast path: whole wave has label 0, mask 1 (w = 0.75) ----
        #pragma unroll
        for (int j = 0; j < 4; ++j) {
            float t     = __expf(xs[j]);                       // exp(x)
            float denom = 1.0f + t;
            float om    = t * __builtin_amdgcn_rcpf(denom);    // sigmoid(x)
            acc += 0.75f * (om * om) * __logf(denom);
        }
    } else {
        // ---- general path (~27% of waves): per-element table gather ----
        int   b0   = a / A_;
        int   row0 = (b0 * ROWS + max(l0, 0)) * C_;
        float m0   = (l0 > -1) ? 1.0f : 0.0f;
        int   row1 = row0;
        float m1   = m0;
        if (c + 3 >= C_) {                 // chunk spans into anchor a+1
            int b1 = (a + 1) / A_;
            row1 = (b1 * ROWS + max(l1, 0)) * C_;
            m1   = (l1 > -1) ? 1.0f : 0.0f;
        }
        #pragma unroll
        for (int j = 0; j < 4; ++j) {
            int cj = c + j;
            int rb; float mf;
            if (cj < C_) { rb = row0 + cj;       mf = m0; }
            else         { rb = row1 + cj - C_;  mf = m1; }
            acc += focal_term(xs[j], tab[rb], mf);
        }
    }
    return acc;
}

// ---------------------------------------------------------------------------
// Kernel 2 (fused): smooth-L1 regression + positive count + focal cls sum.
// Writes per-block partials {reg, cls, cnt} -> no atomics, no pre-zeroing.
// cls loop: unroll-4 across grid stride, all loads hoisted (64 B/thread in
// flight), nontemporal conf stream (read-once).
// ---------------------------------------------------------------------------
__global__ __launch_bounds__(TPB) void fused_kernel(
        const float* __restrict__ conf,
        const float* __restrict__ pred, const float* __restrict__ gtl,
        const int*   __restrict__ lb,   const float* __restrict__ tab,
        float* __restrict__ partials) {
    __shared__ float sm[TPB / 64];
    float reg = 0.0f, cls = 0.0f, cnt = 0.0f;
    const int tid    = blockIdx.x * TPB + threadIdx.x;
    const int stride = gridDim.x * TPB;

    // ---- regression over anchors (5% positives gather pred/gt float4) ----
    for (int a = tid; a < NANCH; a += stride) {
        int l = lb[a];
        if (l > 0) {
            cnt += 1.0f;
            float4 p = ((const float4*)pred)[a];
            float4 g = ((const float4*)gtl)[a];
            reg += sl1(fabsf(p.x - g.x)) + sl1(fabsf(p.y - g.y)) +
                   sl1(fabsf(p.z - g.z)) + sl1(fabsf(p.w - g.w));
        }
    }

    // ---- focal cls over 18M float4 chunks ----
    const f4* cp = (const f4*)conf;
    int ch = tid;
    for (; ch + 3 * stride < NCHUNK; ch += 4 * stride) {
        const int c0 = ch, c1 = ch + stride, c2 = ch + 2 * stride,
                  c3 = ch + 3 * stride;
        // hoist all conf loads (nontemporal: stream, read-once)
        f4 x0 = __builtin_nontemporal_load(cp + c0);
        f4 x1 = __builtin_nontemporal_load(cp + c1);
        f4 x2 = __builtin_nontemporal_load(cp + c2);
        f4 x3 = __builtin_nontemporal_load(cp + c3);
        // hoist all label loads
        int e0 = c0 * 4, a0 = e0 / C_, cc0 = e0 - a0 * C_;
        int e1 = c1 * 4, a1 = e1 / C_, cc1 = e1 - a1 * C_;
        int e2 = c2 * 4, a2 = e2 / C_, cc2 = e2 - a2 * C_;
        int e3 = c3 * 4, a3 = e3 / C_, cc3 = e3 - a3 * C_;
        int l00 = lb[a0], l01 = (cc0 + 3 >= C_) ? lb[a0 + 1] : l00;
        int l10 = lb[a1], l11 = (cc1 + 3 >= C_) ? lb[a1 + 1] : l10;
        int l20 = lb[a2], l21 = (cc2 + 3 >= C_) ? lb[a2 + 1] : l20;
        int l30 = lb[a3], l31 = (cc3 + 3 >= C_) ? lb[a3 + 1] : l30;
        cls += process_chunk(x0, a0, cc0, l00, l01, tab);
        cls += process_chunk(x1, a1, cc1, l10, l11, tab);
        cls += process_chunk(x2, a2, cc2, l20, l21, tab);
        cls += process_chunk(x3, a3, cc3, l30, l31, tab);
    }
    for (; ch < NCHUNK; ch += stride) {
        f4 x = __builtin_nontemporal_load(cp + ch);
        int e = ch * 4, a = e / C_, c = e - a * C_;
        int l0 = lb[a];
        int l1 = (c + 3 >= C_) ? lb[a + 1] : l0;
        cls += process_chunk(x, a, c, l0, l1, tab);
    }

    float rb = block_reduce_sum<TPB / 64>(reg, sm);
    float cb = block_reduce_sum<TPB / 64>(cls, sm);
    float nb = block_reduce_sum<TPB / 64>(cnt, sm);
    if (threadIdx.x == 0) {
        float4 w; w.x = rb; w.y = cb; w.z = nb; w.w = 0.0f;
        ((float4*)partials)[blockIdx.x] = w;
    }
}

// ---------------------------------------------------------------------------
// Kernel 3: reduce per-block partials, write the two scalar outputs.
// ---------------------------------------------------------------------------
__global__ __launch_bounds__(FTPB) void finalize(
        const float* __restrict__ partials, float* __restrict__ out) {
    __shared__ float sm[FTPB / 64];
    float r = 0.0f, c = 0.0f, n = 0.0f;
    for (int i = threadIdx.x; i < NBLK; i += FTPB) {
        float4 p = ((const float4*)partials)[i];
        r += p.x; c += p.y; n += p.z;
    }
    r = block_reduce_sum<FTPB / 64>(r, sm);
    c = block_reduce_sum<FTPB / 64>(c, sm);
    n = block_reduce_sum<FTPB / 64>(n, sm);
    if (threadIdx.x == 0) {
        float np = fmaxf(1.0f, n);
        out[0] = r / (np * 4.0f);
        out[1] = c / (np * 6.0f);
    }
}

extern "C" void kernel_launch(void* const* d_in, const int* in_sizes, int n_in,
                              void* d_out, int out_size, void* d_ws, size_t ws_size,
                              hipStream_t stream) {
    const float* conf = (const float*)d_in[0];
    const float* pred = (const float*)d_in[1];
    const float* gt   = (const float*)d_in[2];
    const int*   gtl  = (const int*)d_in[3];
    // d_in[4] = counts: unused by the reference computation
    const int*   lb   = (const int*)d_in[5];
    float* out      = (float*)d_out;
    float* partials = (float*)d_ws;                 // NBLK float4 = 128 KB
    float* tab      = (float*)d_ws + 4 * NBLK;      // 25200 floats (100 KB)

    build_table<<<(TABN + TPB - 1) / TPB, TPB, 0, stream>>>(gtl, tab);
    fused_kernel<<<NBLK, TPB, 0, stream>>>(conf, pred, gt, lb, tab, partials);
    finalize<<<1, FTPB, 0, stream>>>(partials, out);
}